// Round 6
// baseline (431.838 us; speedup 1.0000x reference)
//
#include <hip/hip_runtime.h>

typedef __bf16 bf16;
typedef __bf16 bf16x4 __attribute__((ext_vector_type(4)));
typedef __bf16 bf16x8 __attribute__((ext_vector_type(8)));
typedef float f32x4 __attribute__((ext_vector_type(4)));

#define N_ROWS 65536

// ---- packed (PRE-SWIZZLED, k-slice-contiguous) weight layout in d_ws ----
// Each k-slice is contiguous: for row r, word w(0..31): value = W[r][s*32 + ((w>>3)^swz4(r))*8 + (w&7)]
// W1 : 24 slices x 13312 B (208 rows)   | W12: 7 x 7168 B (112 rows)
// W13:  4 slices x  7168 B (112 rows)   | W2 : 4g x 4 x 8192 B (128 rows)
#define W1_E   159744
#define W12_E  25088
#define W13_E  14336
#define W2_E   65536
#define WP_TOTAL (W1_E + W12_E + W13_E + W2_E)        // 264704 elems
#define W12_OFF_B 319488
#define W13_OFF_B 369664
#define W2_OFF_B  398336
#define BP_OFF_BYTES (WP_TOTAL * 2)                   // 529408
#define BP_FLOATS 944
#define ACC_OFF_BYTES (BP_OFF_BYTES + BP_FLOATS * 4)  // 533184 (16B aligned)
#define NCOPY 16
#define P0_IDX (NCOPY * 256)                          // 4096
#define S_IDX0 (P0_IDX + 1)                           // 4097..4112
#define P3_IDX0 (S_IDX0 + NCOPY)                      // 4113..4128
#define ACC_FLOATS (P3_IDX0 + NCOPY)                  // 4129

__device__ inline int swz4(int r) { return (r ^ (r >> 2)) & 3; }

__global__ void pack_kernel(const float* __restrict__ W1, const float* __restrict__ b1,
                            const float* __restrict__ W12, const float* __restrict__ b12,
                            const float* __restrict__ W13, const float* __restrict__ b13,
                            const float* __restrict__ W2, const float* __restrict__ b2,
                            bf16* __restrict__ wp, float* __restrict__ bp) {
  int i = blockIdx.x * 256 + threadIdx.x;
  if (i < WP_TOTAL) {
    float v = 0.0f;
    if (i < W1_E) {
      int s = i / 6656, b = i - s * 6656;
      int r = b >> 5, w = b & 31;
      int k = s * 32 + (((w >> 3) ^ swz4(r)) << 3) + (w & 7);
      if (r < 200) v = W1[r * 768 + k];
    } else if (i < W1_E + W12_E) {
      int j = i - W1_E;
      int s = j / 3584, b = j - s * 3584;
      int r = b >> 5, w = b & 31;
      int k = s * 32 + (((w >> 3) ^ swz4(r)) << 3) + (w & 7);
      if (r < 100 && k < 200) v = W12[r * 200 + k];
    } else if (i < W1_E + W12_E + W13_E) {
      int j = i - (W1_E + W12_E);
      int s = j / 3584, b = j - s * 3584;
      int r = b >> 5, w = b & 31;
      int k = s * 32 + (((w >> 3) ^ swz4(r)) << 3) + (w & 7);
      if (r < 100 && k < 100) v = W13[r * 100 + k];
    } else {
      int j = i - (W1_E + W12_E + W13_E);
      int g = j >> 14, rest = j & 16383;
      int s = rest >> 12, b = rest & 4095;
      int r = b >> 5, w = b & 31;
      int o = g * 128 + r;
      int k = s * 32 + (((w >> 3) ^ swz4(r)) << 3) + (w & 7);
      if (k < 100) v = W2[o * 100 + k];
    }
    wp[i] = (bf16)v;
  } else {
    int j = i - WP_TOTAL;
    if (j < BP_FLOATS) {
      float v = 0.0f;
      if (j < 208)      { if (j < 200) v = b1[j]; }
      else if (j < 320) { int o = j - 208; if (o < 100) v = b12[o]; }
      else if (j < 432) { int o = j - 320; if (o < 100) v = b13[o]; }
      else              { v = b2[j - 432]; }
      bp[j] = v;
    }
  }
}

#define MFMA(a, b, c) __builtin_amdgcn_mfma_f32_16x16x32_bf16((a), (b), (c), 0, 0, 0)

// Direct global->LDS staging of one pre-swizzled weight k-slice.
template<int BYTES>
__device__ inline void stage(const char* __restrict__ src, bf16* __restrict__ dstw, int tid) {
  char* dst = (char*)dstw;
  const int off0 = (tid >> 6) * 1024 + (tid & 63) * 16;
  constexpr int NCH = (BYTES + 4095) / 4096;
#pragma unroll
  for (int j = 0; j < NCH; j++) {
    const int off = j * 4096 + off0;
    if ((BYTES & 4095) == 0 || off < BYTES)
      __builtin_amdgcn_global_load_lds(
          (const __attribute__((address_space(1))) void*)(src + off),
          (__attribute__((address_space(3))) void*)(dst + off),
          16, 0, 0);
  }
}

// Block = 256 threads = 4 waves; each wave runs 16 rows through all 4 layers.
// Layer-1 A operands are k-batched (4 steps = 128 f32 cols) through a
// swizzled per-wave LDS panel: global loads are 512B-contiguous per row
// (streaming), issued at the top of sub-step 0 so they hide under that step's
// MFMA compute and are drained by its closing __syncthreads. No inline asm.
__global__ __launch_bounds__(256, 2) void mlp_main(
    const float* __restrict__ input, const float* __restrict__ h,
    const bf16* __restrict__ wp, const float* __restrict__ bp,
    float* __restrict__ out, float* __restrict__ p0_accum) {
  __shared__ __align__(16) bf16 acts[4][3712];   // x1 16x232 | x2/x3 16x136 overlay
  __shared__ __align__(16) bf16 wbuf[2][6656];   // 2 x 13312 B weight slices
  __shared__ __align__(16) bf16 abuf[4][2048];   // per-wave A batch: 4 kk x 16 rows x 32 elems (swizzled)
  __shared__ float p0red[4];

  const int tid = threadIdx.x;
  const int lane = tid & 63;
  const int wave = tid >> 6;
  const int c16 = lane & 15;
  const int quad = lane >> 4;
  const int m0 = blockIdx.x * 64 + wave * 16;
  const int qs8 = (quad ^ swz4(c16)) * 8;

  const char* wpb = (const char*)wp;
  const float* b1p  = bp;
  const float* b12p = bp + 208;
  const float* b13p = bp + 320;
  const float* b2p  = bp + 432;

  bf16* actw = &acts[wave][0];
  bf16* aw = &abuf[wave][0];

  // ---------------- Layer 1: (16x768) @ W1^T -> 16x208 ----------------
  f32x4 acc1[13];
#pragma unroll
  for (int t = 0; t < 13; t++) acc1[t] = (f32x4){0.f, 0.f, 0.f, 0.f};

  // A-batch machinery. Lane covers 128B of the wave's 16x512B batch panel:
  // instr i reads rows 2i+(lane>>5), bytes (lane&31)*16 .. +16 (contiguous
  // 512B per row-pair per instr -> streaming-friendly).
  f32x4 ar[8];
  auto loadA = [&](int kb) {
#pragma unroll
    for (int i = 0; i < 8; i++) {
      const int row = 2 * i + (lane >> 5);
      const int col = (lane & 31) * 4;
      const float* src = (kb < 4)
          ? (input + (size_t)(m0 + row) * 512 + kb * 128 + col)
          : (h + (size_t)(m0 + row) * 256 + (kb - 4) * 128 + col);
      ar[i] = *(const f32x4*)src;
    }
  };
  // LDS layout elem off = kk*512 + row*32 + (q ^ swz4(row))*8 + e   (per wave)
  auto writeA = [&]() {
    const int kk = (lane & 31) >> 3;
    const int q  = ((lane & 31) >> 1) & 3;
    const int sub = (lane & 1) * 4;
#pragma unroll
    for (int i = 0; i < 8; i++) {
      const int row = 2 * i + (lane >> 5);
      bf16x4 cv;
#pragma unroll
      for (int c = 0; c < 4; c++) cv[c] = (bf16)ar[i][c];
      *(bf16x4*)(aw + kk * 512 + row * 32 + ((q ^ swz4(row)) * 8) + sub) = cv;
    }
  };

  stage<13312>(wpb, wbuf[0], tid);   // weight slice for step 0
  loadA(0);

  for (int kb = 0; kb < 6; kb++) {
    writeA();                        // batch kb -> LDS (waits its own loads only)
    __syncthreads();                 // A-panel (+ pending weight slice) ready
#pragma unroll
    for (int j = 0; j < 4; j++) {
      const int ks = kb * 4 + j;
      if (j == 0 && kb + 1 < 6) loadA(kb + 1);  // next A batch: hides under this step, drains at its barrier
      if (ks + 1 < 24) stage<13312>(wpb + (ks + 1) * 13312, wbuf[(ks + 1) & 1], tid);
      bf16x8 a = *(const bf16x8*)(aw + j * 512 + c16 * 32 + qs8);
      const bf16* buf = wbuf[ks & 1];
#pragma unroll
      for (int t = 0; t < 13; t++) {
        bf16x8 bb = *(const bf16x8*)(buf + (t * 16 + c16) * 32 + qs8);
        acc1[t] = MFMA(a, bb, acc1[t]);
      }
      __syncthreads();               // drains W(ks+1) (+ A-loads at j==0)
    }
  }
#pragma unroll
  for (int t = 0; t < 13; t++) {
    const float bias = b1p[t * 16 + c16];
#pragma unroll
    for (int r = 0; r < 4; r++)
      actw[(quad * 4 + r) * 232 + t * 16 + c16] = (bf16)fmaxf(acc1[t][r] + bias, 0.0f);
  }
  for (int idx = lane; idx < 256; idx += 64)
    actw[(idx >> 4) * 232 + 208 + (idx & 15)] = (bf16)0.0f;

  // ---------------- Layer 2: (16x224) @ W12^T -> 16x112 ----------------
  f32x4 acc2[7];
#pragma unroll
  for (int t = 0; t < 7; t++) acc2[t] = (f32x4){0.f, 0.f, 0.f, 0.f};

  stage<7168>(wpb + W12_OFF_B, wbuf[0], tid);
  __syncthreads();
#pragma unroll
  for (int ks = 0; ks < 7; ks++) {
    if (ks + 1 < 7) stage<7168>(wpb + W12_OFF_B + (ks + 1) * 7168, wbuf[(ks + 1) & 1], tid);
    bf16x8 a = *(const bf16x8*)(actw + c16 * 232 + ks * 32 + quad * 8);
    const bf16* buf = wbuf[ks & 1];
#pragma unroll
    for (int t = 0; t < 7; t++) {
      bf16x8 bb = *(const bf16x8*)(buf + (t * 16 + c16) * 32 + qs8);
      acc2[t] = MFMA(a, bb, acc2[t]);
    }
    __syncthreads();
  }
#pragma unroll
  for (int t = 0; t < 7; t++) {
    const float bias = b12p[t * 16 + c16];
#pragma unroll
    for (int r = 0; r < 4; r++)
      actw[(quad * 4 + r) * 136 + t * 16 + c16] = (bf16)fmaxf(acc2[t][r] + bias, 0.0f);
  }
  for (int idx = lane; idx < 256; idx += 64)
    actw[(idx >> 4) * 136 + 112 + (idx & 15)] = (bf16)0.0f;

  // ---------------- Layer 3: (16x128) @ W13^T -> 16x112 ----------------
  f32x4 acc3[7];
#pragma unroll
  for (int t = 0; t < 7; t++) acc3[t] = (f32x4){0.f, 0.f, 0.f, 0.f};

  stage<7168>(wpb + W13_OFF_B, wbuf[0], tid);
  __syncthreads();
#pragma unroll
  for (int ks = 0; ks < 4; ks++) {
    if (ks + 1 < 4) stage<7168>(wpb + W13_OFF_B + (ks + 1) * 7168, wbuf[(ks + 1) & 1], tid);
    bf16x8 a = *(const bf16x8*)(actw + c16 * 136 + ks * 32 + quad * 8);
    const bf16* buf = wbuf[ks & 1];
#pragma unroll
    for (int t = 0; t < 7; t++) {
      bf16x8 bb = *(const bf16x8*)(buf + (t * 16 + c16) * 32 + qs8);
      acc3[t] = MFMA(a, bb, acc3[t]);
    }
    __syncthreads();
  }
#pragma unroll
  for (int t = 0; t < 7; t++) {
    const float bias = b13p[t * 16 + c16];
#pragma unroll
    for (int r = 0; r < 4; r++)
      actw[(quad * 4 + r) * 136 + t * 16 + c16] = (bf16)fmaxf(acc3[t][r] + bias, 0.0f);
  }
  for (int idx = lane; idx < 256; idx += 64)
    actw[(idx >> 4) * 136 + 112 + (idx & 15)] = (bf16)0.0f;

  // ---------------- Layer 4: (16x128) @ W2^T -> 16x512 (+ part0) ----------------
  float p0local = 0.0f;
  for (int g = 0; g < 4; g++) {
    f32x4 acc4[8];
#pragma unroll
    for (int t = 0; t < 8; t++) acc4[t] = (f32x4){0.f, 0.f, 0.f, 0.f};

    const char* Wg = wpb + W2_OFF_B + g * 32768;
    stage<8192>(Wg, wbuf[0], tid);
    __syncthreads();
#pragma unroll
    for (int ks = 0; ks < 4; ks++) {
      if (ks + 1 < 4) stage<8192>(Wg + (ks + 1) * 8192, wbuf[(ks + 1) & 1], tid);
      bf16x8 a = *(const bf16x8*)(actw + c16 * 136 + ks * 32 + quad * 8);
      const bf16* buf = wbuf[ks & 1];
#pragma unroll
      for (int t = 0; t < 8; t++) {
        bf16x8 bb = *(const bf16x8*)(buf + (t * 16 + c16) * 32 + qs8);
        acc4[t] = MFMA(a, bb, acc4[t]);
      }
      __syncthreads();
    }
#pragma unroll
    for (int t = 0; t < 8; t++) {
      const int o = g * 128 + t * 16 + c16;
      const float bias = b2p[o];
#pragma unroll
      for (int r = 0; r < 4; r++) {
        const int grow = m0 + quad * 4 + r;
        float v = acc4[t][r] + bias;
        out[(size_t)grow * 512 + o] = v;
        if (grow < N_ROWS - 1) {
          float d = v - input[(size_t)(grow + 1) * 512 + o];
          p0local += d * d;
        }
      }
    }
  }
#pragma unroll
  for (int off = 32; off > 0; off >>= 1) p0local += __shfl_down(p0local, off);
  if (lane == 0) p0red[wave] = p0local;
  __syncthreads();
  if (tid == 0) atomicAdd(p0_accum, p0red[0] + p0red[1] + p0red[2] + p0red[3]);
}

// mu / S / part3 over h. 2048 blocks x 32 rows (8/CU of TLP); thread
// (c=t&63, rg=t>>6) covers cols 4c..4c+3, rows start..start+7. All 9 loads
// issued before any math. Atomics NCOPY-spread (colsum AND S/P3).
__global__ __launch_bounds__(256) void reduce_h(const float* __restrict__ h, float* __restrict__ acc) {
  __shared__ f32x4 cbuf[256];
  __shared__ float redS[256];
  __shared__ float redP[256];
  const int t = threadIdx.x;
  const int c = t & 63;
  const int rg = t >> 6;
  const int start = blockIdx.x * 32 + rg * 8;

  const float* base = h + (size_t)start * 256 + c * 4;
  f32x4 v[9];
#pragma unroll
  for (int r = 0; r < 8; r++) v[r] = *(const f32x4*)(base + (size_t)r * 256);
  if (start + 8 < N_ROWS) v[8] = *(const f32x4*)(base + (size_t)8 * 256);
  else                    v[8] = v[7];   // d=0 at the global tail

  f32x4 csum = (f32x4){0.f, 0.f, 0.f, 0.f};
  f32x4 s2v  = (f32x4){0.f, 0.f, 0.f, 0.f};
  f32x4 p3v  = (f32x4){0.f, 0.f, 0.f, 0.f};
#pragma unroll
  for (int r = 0; r < 8; r++) {
    csum += v[r];
    s2v  += v[r] * v[r];
    f32x4 d = v[r + 1] - v[r];
#pragma unroll
    for (int i = 0; i < 4; i++) p3v[i] += __builtin_fabsf(d[i]);
  }
  cbuf[t] = csum;
  redS[t] = s2v[0] + s2v[1] + s2v[2] + s2v[3];
  redP[t] = p3v[0] + p3v[1] + p3v[2] + p3v[3];
  __syncthreads();
  if (rg == 0) {
    f32x4 s = cbuf[c] + cbuf[c + 64] + cbuf[c + 128] + cbuf[c + 192];
    float* dst = acc + (blockIdx.x & (NCOPY - 1)) * 256 + 4 * c;
    atomicAdd(dst + 0, s[0]);
    atomicAdd(dst + 1, s[1]);
    atomicAdd(dst + 2, s[2]);
    atomicAdd(dst + 3, s[3]);
  }
  for (int st = 128; st > 0; st >>= 1) {
    if (t < st) { redS[t] += redS[t + st]; redP[t] += redP[t + st]; }
    __syncthreads();
  }
  if (t == 0) {
    atomicAdd(&acc[S_IDX0 + (blockIdx.x & (NCOPY - 1))], redS[0]);
    atomicAdd(&acc[P3_IDX0 + (blockIdx.x & (NCOPY - 1))], redP[0]);
  }
}

__global__ void finalize(const float* __restrict__ acc, float* __restrict__ out) {
  __shared__ float red[256];
  const int t = threadIdx.x;
  float s = 0.0f;
#pragma unroll
  for (int j = 0; j < NCOPY; j++) s += acc[j * 256 + t];
  red[t] = fabsf(s);
  __syncthreads();
  for (int st = 128; st > 0; st >>= 1) {
    if (t < st) red[t] += red[t + st];
    __syncthreads();
  }
  if (t == 0) {
    float Ssum = 0.f, Psum = 0.f;
#pragma unroll
    for (int j = 0; j < NCOPY; j++) { Ssum += acc[S_IDX0 + j]; Psum += acc[P3_IDX0 + j]; }
    out[(size_t)N_ROWS * 512 + 0] = sqrtf(acc[P0_IDX]) / 65535.0f;
    out[(size_t)N_ROWS * 512 + 1] = red[0] / 65536.0f / 256.0f;
    out[(size_t)N_ROWS * 512 + 2] = fabsf(Ssum / (65536.0f * 256.0f) - 1.0f);
    out[(size_t)N_ROWS * 512 + 3] = Psum / (65535.0f * 256.0f);
  }
}

extern "C" void kernel_launch(void* const* d_in, const int* in_sizes, int n_in,
                              void* d_out, int out_size, void* d_ws, size_t ws_size,
                              hipStream_t stream) {
  const float* input = (const float*)d_in[0];
  const float* h   = (const float*)d_in[1];
  const float* W1  = (const float*)d_in[2];
  const float* b1  = (const float*)d_in[3];
  const float* W12 = (const float*)d_in[4];
  const float* b12 = (const float*)d_in[5];
  const float* W13 = (const float*)d_in[6];
  const float* b13 = (const float*)d_in[7];
  const float* W2  = (const float*)d_in[8];
  const float* b2  = (const float*)d_in[9];
  float* out = (float*)d_out;

  bf16* wp = (bf16*)d_ws;
  float* bp = (float*)((char*)d_ws + BP_OFF_BYTES);
  float* acc = (float*)((char*)d_ws + ACC_OFF_BYTES);

  hipMemsetAsync(acc, 0, ACC_FLOATS * sizeof(float), stream);
  pack_kernel<<<(WP_TOTAL + BP_FLOATS + 255) / 256, 256, 0, stream>>>(
      W1, b1, W12, b12, W13, b13, W2, b2, wp, bp);
  mlp_main<<<N_ROWS / 64, 256, 0, stream>>>(input, h, wp, bp, out, acc + P0_IDX);
  reduce_h<<<N_ROWS / 32, 256, 0, stream>>>(h, acc);
  finalize<<<1, 256, 0, stream>>>(acc, out);
}

// Round 7
// 408.510 us; speedup vs baseline: 1.0571x; 1.0571x over previous
//
#include <hip/hip_runtime.h>

typedef __bf16 bf16;
typedef __bf16 bf16x4 __attribute__((ext_vector_type(4)));
typedef __bf16 bf16x8 __attribute__((ext_vector_type(8)));
typedef float f32x4 __attribute__((ext_vector_type(4)));

#define N_ROWS 65536

// ---- packed (PRE-SWIZZLED, k-slice-contiguous) weight layout in d_ws ----
// Each k-slice is contiguous: for row r, word w(0..31): value = W[r][s*32 + ((w>>3)^swz4(r))*8 + (w&7)]
// W1 : 24 slices x 13312 B (208 rows)   | W12: 7 x 7168 B (112 rows)
// W13:  4 slices x  7168 B (112 rows)   | W2 : 4g x 4 x 8192 B (128 rows)
#define W1_E   159744
#define W12_E  25088
#define W13_E  14336
#define W2_E   65536
#define WP_TOTAL (W1_E + W12_E + W13_E + W2_E)        // 264704 elems
#define W12_OFF_B 319488
#define W13_OFF_B 369664
#define W2_OFF_B  398336
#define BP_OFF_BYTES (WP_TOTAL * 2)                   // 529408
#define BP_FLOATS 944
#define ACC_OFF_BYTES (BP_OFF_BYTES + BP_FLOATS * 4)  // 533184 (16B aligned)
#define NCOPY 16
#define P0_IDX (NCOPY * 256)                          // 4096
#define S_IDX0 (P0_IDX + 1)                           // 4097..4112
#define P3_IDX0 (S_IDX0 + NCOPY)                      // 4113..4128
#define ACC_FLOATS (P3_IDX0 + NCOPY)                  // 4129

__device__ inline int swz4(int r) { return (r ^ (r >> 2)) & 3; }

__global__ void pack_kernel(const float* __restrict__ W1, const float* __restrict__ b1,
                            const float* __restrict__ W12, const float* __restrict__ b12,
                            const float* __restrict__ W13, const float* __restrict__ b13,
                            const float* __restrict__ W2, const float* __restrict__ b2,
                            bf16* __restrict__ wp, float* __restrict__ bp) {
  int i = blockIdx.x * 256 + threadIdx.x;
  if (i < WP_TOTAL) {
    float v = 0.0f;
    if (i < W1_E) {
      int s = i / 6656, b = i - s * 6656;
      int r = b >> 5, w = b & 31;
      int k = s * 32 + (((w >> 3) ^ swz4(r)) << 3) + (w & 7);
      if (r < 200) v = W1[r * 768 + k];
    } else if (i < W1_E + W12_E) {
      int j = i - W1_E;
      int s = j / 3584, b = j - s * 3584;
      int r = b >> 5, w = b & 31;
      int k = s * 32 + (((w >> 3) ^ swz4(r)) << 3) + (w & 7);
      if (r < 100 && k < 200) v = W12[r * 200 + k];
    } else if (i < W1_E + W12_E + W13_E) {
      int j = i - (W1_E + W12_E);
      int s = j / 3584, b = j - s * 3584;
      int r = b >> 5, w = b & 31;
      int k = s * 32 + (((w >> 3) ^ swz4(r)) << 3) + (w & 7);
      if (r < 100 && k < 100) v = W13[r * 100 + k];
    } else {
      int j = i - (W1_E + W12_E + W13_E);
      int g = j >> 14, rest = j & 16383;
      int s = rest >> 12, b = rest & 4095;
      int r = b >> 5, w = b & 31;
      int o = g * 128 + r;
      int k = s * 32 + (((w >> 3) ^ swz4(r)) << 3) + (w & 7);
      if (k < 100) v = W2[o * 100 + k];
    }
    wp[i] = (bf16)v;
  } else {
    int j = i - WP_TOTAL;
    if (j < BP_FLOATS) {
      float v = 0.0f;
      if (j < 208)      { if (j < 200) v = b1[j]; }
      else if (j < 320) { int o = j - 208; if (o < 100) v = b12[o]; }
      else if (j < 432) { int o = j - 320; if (o < 100) v = b13[o]; }
      else              { v = b2[j - 432]; }
      bp[j] = v;
    }
  }
}

#define MFMA(a, b, c) __builtin_amdgcn_mfma_f32_16x16x32_bf16((a), (b), (c), 0, 0, 0)

// Direct global->LDS staging of one pre-swizzled weight k-slice.
template<int BYTES>
__device__ inline void stage(const char* __restrict__ src, bf16* __restrict__ dstw, int tid) {
  char* dst = (char*)dstw;
  const int off0 = (tid >> 6) * 1024 + (tid & 63) * 16;
  constexpr int NCH = (BYTES + 4095) / 4096;
#pragma unroll
  for (int j = 0; j < NCH; j++) {
    const int off = j * 4096 + off0;
    if ((BYTES & 4095) == 0 || off < BYTES)
      __builtin_amdgcn_global_load_lds(
          (const __attribute__((address_space(1))) void*)(src + off),
          (__attribute__((address_space(3))) void*)(dst + off),
          16, 0, 0);
  }
}

// Block = 256 threads = 4 waves; each wave runs 16 rows through all 4 layers.
// FUSED: the h statistics (colsum/mu, S, part3) are accumulated in-register
// from the layer-1 h A-batches (each h element passes through exactly once);
// row-pair |d| via __shfl_xor(...,32) (pair rows live in opposite lane
// halves); 16-row-boundary pairs via one small L2-hot re-read. reduce_h
// kernel is eliminated. A-batch LDS panel is aliased onto the acts region
// (temporally disjoint), cutting LDS to ~56.8 KB.
__global__ __launch_bounds__(256, 2) void mlp_main(
    const float* __restrict__ input, const float* __restrict__ h,
    const bf16* __restrict__ wp, const float* __restrict__ bp,
    float* __restrict__ out, float* __restrict__ acc) {
  __shared__ __align__(16) bf16 acts[4][3712];   // x1 16x232 | x2/x3 16x136 | abuf/hred overlays
  __shared__ __align__(16) bf16 wbuf[2][6656];   // 2 x 13312 B weight slices
  __shared__ float wred[4][3];                   // per-wave {p0, S, P3} partials

  const int tid = threadIdx.x;
  const int lane = tid & 63;
  const int wave = tid >> 6;
  const int c16 = lane & 15;
  const int quad = lane >> 4;
  const int m0 = blockIdx.x * 64 + wave * 16;
  const int qs8 = (quad ^ swz4(c16)) * 8;

  const char* wpb = (const char*)wp;
  const float* b1p  = bp;
  const float* b12p = bp + 208;
  const float* b13p = bp + 320;
  const float* b2p  = bp + 432;

  bf16* actw = &acts[wave][0];
  bf16* aw = actw;                 // A-batch panel aliases acts (x1 written after L1 loop)

  // fused h-stat accumulators
  f32x4 csA = (f32x4){0.f, 0.f, 0.f, 0.f};   // colsum partial, cols 0..127 half
  f32x4 csB = (f32x4){0.f, 0.f, 0.f, 0.f};   // colsum partial, cols 128..255 half
  float s2loc = 0.0f, p3loc = 0.0f;

  // ---------------- Layer 1: (16x768) @ W1^T -> 16x208 ----------------
  f32x4 acc1[13];
#pragma unroll
  for (int t = 0; t < 13; t++) acc1[t] = (f32x4){0.f, 0.f, 0.f, 0.f};

  // A-batch: lane covers rows 2i+(lane>>5), cols (lane&31)*4 (512B-contiguous
  // per row-pair per instr).
  f32x4 ar[8];
  auto loadA = [&](int kb) {
#pragma unroll
    for (int i = 0; i < 8; i++) {
      const int row = 2 * i + (lane >> 5);
      const int col = (lane & 31) * 4;
      const float* src = (kb < 4)
          ? (input + (size_t)(m0 + row) * 512 + kb * 128 + col)
          : (h + (size_t)(m0 + row) * 256 + (kb - 4) * 128 + col);
      ar[i] = *(const f32x4*)src;
    }
  };
  auto writeA = [&]() {
    const int kk = (lane & 31) >> 3;
    const int q  = ((lane & 31) >> 1) & 3;
    const int sub = (lane & 1) * 4;
#pragma unroll
    for (int i = 0; i < 8; i++) {
      const int row = 2 * i + (lane >> 5);
      bf16x4 cv;
#pragma unroll
      for (int c = 0; c < 4; c++) cv[c] = (bf16)ar[i][c];
      *(bf16x4*)(aw + kk * 512 + row * 32 + ((q ^ swz4(row)) * 8) + sub) = cv;
    }
  };

  stage<13312>(wpb, wbuf[0], tid);   // weight slice for step 0
  loadA(0);

  for (int kb = 0; kb < 6; kb++) {
    writeA();                        // batch kb -> LDS (waits its own loads only)
    if (kb >= 4) {
      // h-stats for this batch (rows m0..m0+15, cols (kb-4)*128 + lane-cols).
      f32x4* cs = (kb == 4) ? &csA : &csB;
#pragma unroll
      for (int i = 0; i < 8; i++) {
        f32x4 oth;
#pragma unroll
        for (int c = 0; c < 4; c++) oth[c] = __shfl_xor(ar[i][c], 32);
        *cs += ar[i];
#pragma unroll
        for (int c = 0; c < 4; c++) s2loc += ar[i][c] * ar[i][c];
        if (lane < 32) {            // pair (2i, 2i+1)
#pragma unroll
          for (int c = 0; c < 4; c++) p3loc += __builtin_fabsf(oth[c] - ar[i][c]);
        } else if (i >= 1) {        // pair (2i-1, 2i): oth = row 2i, ar[i-1] = row 2i-1
#pragma unroll
          for (int c = 0; c < 4; c++) p3loc += __builtin_fabsf(oth[c] - ar[i - 1][c]);
        }
      }
    }
    __syncthreads();                 // A-panel (+ pending weight slice) ready
#pragma unroll
    for (int j = 0; j < 4; j++) {
      const int ks = kb * 4 + j;
      if (j == 0 && kb + 1 < 6) loadA(kb + 1);  // next A batch hides under this step
      if (ks + 1 < 24) stage<13312>(wpb + (ks + 1) * 13312, wbuf[(ks + 1) & 1], tid);
      bf16x8 a = *(const bf16x8*)(aw + j * 512 + c16 * 32 + qs8);
      const bf16* buf = wbuf[ks & 1];
#pragma unroll
      for (int t = 0; t < 13; t++) {
        bf16x8 bb = *(const bf16x8*)(buf + (t * 16 + c16) * 32 + qs8);
        acc1[t] = MFMA(a, bb, acc1[t]);
      }
      __syncthreads();               // drains W(ks+1) (+ A-loads at j==0)
    }
  }
#pragma unroll
  for (int t = 0; t < 13; t++) {
    const float bias = b1p[t * 16 + c16];
#pragma unroll
    for (int r = 0; r < 4; r++)
      actw[(quad * 4 + r) * 232 + t * 16 + c16] = (bf16)fmaxf(acc1[t][r] + bias, 0.0f);
  }
  for (int idx = lane; idx < 256; idx += 64)
    actw[(idx >> 4) * 232 + 208 + (idx & 15)] = (bf16)0.0f;

  // ---------------- Layer 2: (16x224) @ W12^T -> 16x112 ----------------
  f32x4 acc2[7];
#pragma unroll
  for (int t = 0; t < 7; t++) acc2[t] = (f32x4){0.f, 0.f, 0.f, 0.f};

  stage<7168>(wpb + W12_OFF_B, wbuf[0], tid);
  __syncthreads();
#pragma unroll
  for (int ks = 0; ks < 7; ks++) {
    if (ks + 1 < 7) stage<7168>(wpb + W12_OFF_B + (ks + 1) * 7168, wbuf[(ks + 1) & 1], tid);
    bf16x8 a = *(const bf16x8*)(actw + c16 * 232 + ks * 32 + quad * 8);
    const bf16* buf = wbuf[ks & 1];
#pragma unroll
    for (int t = 0; t < 7; t++) {
      bf16x8 bb = *(const bf16x8*)(buf + (t * 16 + c16) * 32 + qs8);
      acc2[t] = MFMA(a, bb, acc2[t]);
    }
    __syncthreads();
  }
#pragma unroll
  for (int t = 0; t < 7; t++) {
    const float bias = b12p[t * 16 + c16];
#pragma unroll
    for (int r = 0; r < 4; r++)
      actw[(quad * 4 + r) * 136 + t * 16 + c16] = (bf16)fmaxf(acc2[t][r] + bias, 0.0f);
  }
  for (int idx = lane; idx < 256; idx += 64)
    actw[(idx >> 4) * 136 + 112 + (idx & 15)] = (bf16)0.0f;

  // ---------------- Layer 3: (16x128) @ W13^T -> 16x112 ----------------
  f32x4 acc3[7];
#pragma unroll
  for (int t = 0; t < 7; t++) acc3[t] = (f32x4){0.f, 0.f, 0.f, 0.f};

  stage<7168>(wpb + W13_OFF_B, wbuf[0], tid);
  __syncthreads();
#pragma unroll
  for (int ks = 0; ks < 4; ks++) {
    if (ks + 1 < 4) stage<7168>(wpb + W13_OFF_B + (ks + 1) * 7168, wbuf[(ks + 1) & 1], tid);
    bf16x8 a = *(const bf16x8*)(actw + c16 * 136 + ks * 32 + quad * 8);
    const bf16* buf = wbuf[ks & 1];
#pragma unroll
    for (int t = 0; t < 7; t++) {
      bf16x8 bb = *(const bf16x8*)(buf + (t * 16 + c16) * 32 + qs8);
      acc3[t] = MFMA(a, bb, acc3[t]);
    }
    __syncthreads();
  }
#pragma unroll
  for (int t = 0; t < 7; t++) {
    const float bias = b13p[t * 16 + c16];
#pragma unroll
    for (int r = 0; r < 4; r++)
      actw[(quad * 4 + r) * 136 + t * 16 + c16] = (bf16)fmaxf(acc3[t][r] + bias, 0.0f);
  }
  for (int idx = lane; idx < 256; idx += 64)
    actw[(idx >> 4) * 136 + 112 + (idx & 15)] = (bf16)0.0f;

  // ---------------- Layer 4: (16x128) @ W2^T -> 16x512 (+ part0) ----------------
  float p0local = 0.0f;
  for (int g = 0; g < 4; g++) {
    f32x4 acc4[8];
#pragma unroll
    for (int t = 0; t < 8; t++) acc4[t] = (f32x4){0.f, 0.f, 0.f, 0.f};

    const char* Wg = wpb + W2_OFF_B + g * 32768;
    stage<8192>(Wg, wbuf[0], tid);
    __syncthreads();
#pragma unroll
    for (int ks = 0; ks < 4; ks++) {
      if (ks + 1 < 4) stage<8192>(Wg + (ks + 1) * 8192, wbuf[(ks + 1) & 1], tid);
      bf16x8 a = *(const bf16x8*)(actw + c16 * 136 + ks * 32 + quad * 8);
      const bf16* buf = wbuf[ks & 1];
#pragma unroll
      for (int t = 0; t < 8; t++) {
        bf16x8 bb = *(const bf16x8*)(buf + (t * 16 + c16) * 32 + qs8);
        acc4[t] = MFMA(a, bb, acc4[t]);
      }
      __syncthreads();
    }
#pragma unroll
    for (int t = 0; t < 8; t++) {
      const int o = g * 128 + t * 16 + c16;
      const float bias = b2p[o];
#pragma unroll
      for (int r = 0; r < 4; r++) {
        const int grow = m0 + quad * 4 + r;
        float v = acc4[t][r] + bias;
        out[(size_t)grow * 512 + o] = v;
        if (grow < N_ROWS - 1) {
          float d = v - input[(size_t)(grow + 1) * 512 + o];
          p0local += d * d;
        }
      }
    }
  }

  // ---------------- fused-reduction epilogue ----------------
  // boundary pairs (r % 16 == 15): one per 16-row tile; L2-hot re-read.
  {
    const int p = tid >> 6, cq = tid & 63;
    const int rowA = blockIdx.x * 64 + p * 16 + 15;
    if (rowA + 1 < N_ROWS) {
      f32x4 a = *(const f32x4*)(h + (size_t)rowA * 256 + cq * 4);
      f32x4 b = *(const f32x4*)(h + (size_t)(rowA + 1) * 256 + cq * 4);
#pragma unroll
      for (int c = 0; c < 4; c++) p3loc += __builtin_fabsf(b[c] - a[c]);
    }
  }
  // combine lane-halves of the colsum partials (both halves then hold totals)
#pragma unroll
  for (int c = 0; c < 4; c++) {
    csA[c] += __shfl_xor(csA[c], 32);
    csB[c] += __shfl_xor(csB[c], 32);
  }
  // block colsum reduce via LDS aliased onto dead acts region
  f32x4* hred = (f32x4*)&acts[0][0];   // 4 waves x 64 col-quads x 16B = 4 KB
  if (lane < 32) hred[wave * 64 + lane] = csA;
  else           hred[wave * 64 + 32 + (lane & 31)] = csB;
  // per-wave scalar reductions
#pragma unroll
  for (int off = 32; off > 0; off >>= 1) {
    p0local += __shfl_down(p0local, off);
    s2loc   += __shfl_down(s2loc, off);
    p3loc   += __shfl_down(p3loc, off);
  }
  if (lane == 0) { wred[wave][0] = p0local; wred[wave][1] = s2loc; wred[wave][2] = p3loc; }
  __syncthreads();
  if (tid < 64) {
    f32x4 tot = hred[tid] + hred[64 + tid] + hred[128 + tid] + hred[192 + tid];
    float* dst = acc + (blockIdx.x & (NCOPY - 1)) * 256 + tid * 4;
    atomicAdd(dst + 0, tot[0]);
    atomicAdd(dst + 1, tot[1]);
    atomicAdd(dst + 2, tot[2]);
    atomicAdd(dst + 3, tot[3]);
  }
  if (tid == 0) {
    atomicAdd(&acc[P0_IDX], wred[0][0] + wred[1][0] + wred[2][0] + wred[3][0]);
    atomicAdd(&acc[S_IDX0 + (blockIdx.x & (NCOPY - 1))], wred[0][1] + wred[1][1] + wred[2][1] + wred[3][1]);
    atomicAdd(&acc[P3_IDX0 + (blockIdx.x & (NCOPY - 1))], wred[0][2] + wred[1][2] + wred[2][2] + wred[3][2]);
  }
}

__global__ void finalize(const float* __restrict__ acc, float* __restrict__ out) {
  __shared__ float red[256];
  const int t = threadIdx.x;
  float s = 0.0f;
#pragma unroll
  for (int j = 0; j < NCOPY; j++) s += acc[j * 256 + t];
  red[t] = fabsf(s);
  __syncthreads();
  for (int st = 128; st > 0; st >>= 1) {
    if (t < st) red[t] += red[t + st];
    __syncthreads();
  }
  if (t == 0) {
    float Ssum = 0.f, Psum = 0.f;
#pragma unroll
    for (int j = 0; j < NCOPY; j++) { Ssum += acc[S_IDX0 + j]; Psum += acc[P3_IDX0 + j]; }
    out[(size_t)N_ROWS * 512 + 0] = sqrtf(acc[P0_IDX]) / 65535.0f;
    out[(size_t)N_ROWS * 512 + 1] = red[0] / 65536.0f / 256.0f;
    out[(size_t)N_ROWS * 512 + 2] = fabsf(Ssum / (65536.0f * 256.0f) - 1.0f);
    out[(size_t)N_ROWS * 512 + 3] = Psum / (65535.0f * 256.0f);
  }
}

extern "C" void kernel_launch(void* const* d_in, const int* in_sizes, int n_in,
                              void* d_out, int out_size, void* d_ws, size_t ws_size,
                              hipStream_t stream) {
  const float* input = (const float*)d_in[0];
  const float* h   = (const float*)d_in[1];
  const float* W1  = (const float*)d_in[2];
  const float* b1  = (const float*)d_in[3];
  const float* W12 = (const float*)d_in[4];
  const float* b12 = (const float*)d_in[5];
  const float* W13 = (const float*)d_in[6];
  const float* b13 = (const float*)d_in[7];
  const float* W2  = (const float*)d_in[8];
  const float* b2  = (const float*)d_in[9];
  float* out = (float*)d_out;

  bf16* wp = (bf16*)d_ws;
  float* bp = (float*)((char*)d_ws + BP_OFF_BYTES);
  float* acc = (float*)((char*)d_ws + ACC_OFF_BYTES);

  hipMemsetAsync(acc, 0, ACC_FLOATS * sizeof(float), stream);
  pack_kernel<<<(WP_TOTAL + BP_FLOATS + 255) / 256, 256, 0, stream>>>(
      W1, b1, W12, b12, W13, b13, W2, b2, wp, bp);
  mlp_main<<<N_ROWS / 64, 256, 0, stream>>>(input, h, wp, bp, out, acc);
  finalize<<<1, 256, 0, stream>>>(acc, out);
}